// Round 4
// baseline (73.071 us; speedup 1.0000x reference)
//
#include <hip/hip_runtime.h>

// ALS gather-dot: out[b] = dot(user[loc[b,0], :], goods[:, loc[b,1]])
// user: [500000, 128] f32 row-major; goods: [128, 500000] f32 row-major.
//
// R3: row-sweep gather. Sort items by goods-column (counting sort, emits
// sorted (urow,gcol,idx) triples). Gather kernel: block = 64 consecutive
// sorted items (lane <-> item), 8 waves x 16 goods-rows each. One gather
// instruction = 64 ascending columns in a ~8KB window of ONE goods row
// (2-4 DRAM pages) instead of 64 lanes spanning 127 MB (64 pages).

#define KDIM 128
#define GOODS_NUM 500000
#define NBUCKET 15625          // 500000/32: 128B-line buckets
#define WPB 8                  // waves per gather block
#define RPW 16                 // rows per wave (8*16 = 128)

// ---------------- Kernel A: counting sort by gcol>>5, emit triples ----------
__global__ __launch_bounds__(1024) void als_bucket_sort(
    const int* __restrict__ loc,
    int* __restrict__ s_urow, int* __restrict__ s_gcol, int* __restrict__ s_idx,
    int batch)
{
    __shared__ int hist[NBUCKET];   // 62.5 KB
    __shared__ int wsum[16];
    const int t = threadIdx.x;
    const int lane = t & 63, wid = t >> 6;

    for (int i = t; i < NBUCKET; i += 1024) hist[i] = 0;
    __syncthreads();

    const int2* loc2 = reinterpret_cast<const int2*>(loc);
    for (int i = t; i < batch; i += 1024)
        atomicAdd(&hist[loc2[i].y >> 5], 1);
    __syncthreads();

    // exclusive scan over hist
    const int CH = 16;                 // 1024*16 >= 15625
    int local_excl[CH];
    int sum = 0;
    const int base = t * CH;
    #pragma unroll
    for (int c = 0; c < CH; ++c) {
        int idx = base + c;
        int v = (idx < NBUCKET) ? hist[idx] : 0;
        local_excl[c] = sum;
        sum += v;
    }
    int x = sum;
    #pragma unroll
    for (int off = 1; off < 64; off <<= 1) {
        int y = __shfl_up(x, off, 64);
        if (lane >= off) x += y;
    }
    if (lane == 63) wsum[wid] = x;
    __syncthreads();
    int woff = 0;
    for (int w = 0; w < wid; ++w) woff += wsum[w];
    const int chunk_excl = woff + x - sum;
    #pragma unroll
    for (int c = 0; c < CH; ++c) {
        int idx = base + c;
        if (idx < NBUCKET) hist[idx] = chunk_excl + local_excl[c];
    }
    __syncthreads();

    // scatter sorted triples (within-bucket order nondeterministic; output
    // values are permutation-invariant -> harness determinism holds)
    for (int i = t; i < batch; i += 1024) {
        int2 l = loc2[i];
        int pos = atomicAdd(&hist[l.y >> 5], 1);
        s_urow[pos] = l.x;
        s_gcol[pos] = l.y;
        s_idx[pos]  = i;
    }
}

// ---------------- Kernel B: row-sweep gather-dot ----------------------------
__global__ __launch_bounds__(WPB * 64) void als_row_sweep(
    const float* __restrict__ user,
    const float* __restrict__ goods,
    const int* __restrict__ s_urow,
    const int* __restrict__ s_gcol,
    const int* __restrict__ s_idx,
    float* __restrict__ out,
    int batch)
{
    __shared__ float accs[WPB][64];

    // chunked XCD swizzle (gridDim % 8 == 0): each XCD sweeps a contiguous
    // 1/8 of the sorted column range
    const int chunk = gridDim.x >> 3;
    const int blk = (blockIdx.x & 7) * chunk + (blockIdx.x >> 3);

    const int lane = threadIdx.x & 63;
    const int w    = threadIdx.x >> 6;
    const int item = blk * 64 + lane;
    if (item >= batch) return;

    const int urow = s_urow[item];   // coalesced
    const int gcol = s_gcol[item];   // coalesced, ascending across lanes

    const float* up = user + (size_t)urow * KDIM + w * RPW;
    const float* gp = goods + (size_t)(w * RPW) * GOODS_NUM + (size_t)gcol;

    // user chunk: 16 floats, per-lane contiguous (4x float4)
    float uu[RPW];
    *reinterpret_cast<float4*>(&uu[0])  = *reinterpret_cast<const float4*>(up + 0);
    *reinterpret_cast<float4*>(&uu[4])  = *reinterpret_cast<const float4*>(up + 4);
    *reinterpret_cast<float4*>(&uu[8])  = *reinterpret_cast<const float4*>(up + 8);
    *reinterpret_cast<float4*>(&uu[12]) = *reinterpret_cast<const float4*>(up + 12);

    // goods: 16 row-gathers, each 64 ascending cols in a ~8KB window
    float g[RPW];
    #pragma unroll
    for (int r = 0; r < RPW; ++r)
        g[r] = gp[(size_t)r * GOODS_NUM];

    float acc = 0.f;
    #pragma unroll
    for (int r = 0; r < RPW; ++r)
        acc = fmaf(uu[r], g[r], acc);

    accs[w][lane] = acc;
    __syncthreads();

    if (w == 0) {
        float s = 0.f;
        #pragma unroll
        for (int q = 0; q < WPB; ++q) s += accs[q][lane];
        out[s_idx[item]] = s;
    }
}

extern "C" void kernel_launch(void* const* d_in, const int* in_sizes, int n_in,
                              void* d_out, int out_size, void* d_ws, size_t ws_size,
                              hipStream_t stream)
{
    const float* user  = (const float*)d_in[0];
    const float* goods = (const float*)d_in[1];
    const int*   loc   = (const int*)d_in[2];
    float* out = (float*)d_out;

    const int batch = out_size;                 // 16384
    int* s_urow = (int*)d_ws;
    int* s_gcol = s_urow + batch;
    int* s_idx  = s_gcol + batch;

    als_bucket_sort<<<1, 1024, 0, stream>>>(loc, s_urow, s_gcol, s_idx, batch);

    const int blocks = (batch + 63) / 64;       // 256, divisible by 8
    als_row_sweep<<<blocks, WPB * 64, 0, stream>>>(
        user, goods, s_urow, s_gcol, s_idx, out, batch);
}

// Round 6
// 45.041 us; speedup vs baseline: 1.6223x; 1.6223x over previous
//
#include <hip/hip_runtime.h>

// ALS gather-dot: out[b] = dot(user[loc[b,0], :], goods[:, loc[b,1]])
// user: [500000, 128] f32 row-major   -> row gather, contiguous (512 B/row)
// goods: [128, 500000] f32 row-major  -> column gather, stride 2 MB (scattered)
// location: [16384, 2] int            -> out: [16384] f32
//
// R5 = R4 with the compile fix: __builtin_nontemporal_load needs a native
// clang vector type, not HIP_vector_type. Evidence so far: 4x MLP flat (R1),
// sorted dedup flat (R2), row-sweep worse (R3) -> scatter is ~90% of
// achievable read BW at 128B line granule (2.1M lines * 128B = 268MB / 47us
// = 5.7 TB/s vs 6.3-6.9 TB/s ceiling). Zero reuse on all streams -> nt loads
// skip cache allocation.

#define KDIM 128
#define GOODS_NUM 500000

typedef float floatx2 __attribute__((ext_vector_type(2)));

__global__ __launch_bounds__(256) void als_gather_dot(
    const float* __restrict__ user,
    const float* __restrict__ goods,
    const int* __restrict__ loc,
    float* __restrict__ out,
    int batch)
{
    const int gtid = blockIdx.x * blockDim.x + threadIdx.x;
    const int wave = gtid >> 6;          // one wave64 per output element
    const int lane = threadIdx.x & 63;
    if (wave >= batch) return;

    const int urow = loc[wave * 2 + 0];
    const int gcol = loc[wave * 2 + 1];

    // u row: contiguous 128 floats; lane i takes elements 2i, 2i+1
    const floatx2 uv = __builtin_nontemporal_load(
        reinterpret_cast<const floatx2*>(user + (size_t)urow * KDIM + (size_t)(lane * 2)));

    // g column: stride GOODS_NUM floats (2 MB) -> inherently scattered
    const float g0 = __builtin_nontemporal_load(
        goods + (size_t)(lane * 2) * GOODS_NUM + (size_t)gcol);
    const float g1 = __builtin_nontemporal_load(
        goods + (size_t)(lane * 2 + 1) * GOODS_NUM + (size_t)gcol);

    float s = uv.x * g0 + uv.y * g1;

    // wave64 butterfly reduction
    #pragma unroll
    for (int off = 32; off >= 1; off >>= 1)
        s += __shfl_xor(s, off, 64);

    if (lane == 0) out[wave] = s;
}

extern "C" void kernel_launch(void* const* d_in, const int* in_sizes, int n_in,
                              void* d_out, int out_size, void* d_ws, size_t ws_size,
                              hipStream_t stream)
{
    const float* user  = (const float*)d_in[0];
    const float* goods = (const float*)d_in[1];
    const int*   loc   = (const int*)d_in[2];
    float* out = (float*)d_out;

    const int batch = out_size;                 // 16384 outputs
    const int threads = 256;                    // 4 waves/block
    const int blocks = (batch * 64 + threads - 1) / threads;   // 4096
    als_gather_dot<<<blocks, threads, 0, stream>>>(user, goods, loc, out, batch);
}